// Round 15
// baseline (635.712 us; speedup 1.0000x reference)
//
#include <hip/hip_runtime.h>

typedef __attribute__((ext_vector_type(8))) short bf16x8;
typedef __attribute__((ext_vector_type(4))) float f32x4;
typedef __attribute__((ext_vector_type(4))) unsigned short us4;

__device__ __forceinline__ float b2f(unsigned short h) {
  union { unsigned int u; float f; } v; v.u = ((unsigned int)h) << 16; return v.f;
}
__device__ __forceinline__ unsigned short f2b(float f) {
  union { float f; unsigned int u; } v; v.f = f;
  unsigned int r = v.u + 0x7fffu + ((v.u >> 16) & 1u);
  return (unsigned short)(r >> 16);
}

// scale a bf16x8 A-fragment by a per-lane scalar (round-half-up — cheap, unbiased enough)
__device__ __forceinline__ bf16x8 scale8(bf16x8 a, float d) {
  bf16x8 r;
#pragma unroll
  for (int i = 0; i < 8; ++i) {
    union { unsigned int u; float f; } v;
    v.u = ((unsigned int)(unsigned short)a[i]) << 16;
    v.f *= d;
    r[i] = (short)((v.u + 0x8000u) >> 16);
  }
  return r;
}

// ---------------- fp32 -> bf16 bulk convert ----------------
__global__ void f2b_kernel(const float* __restrict__ in, unsigned short* __restrict__ out, int n4) {
  int i = blockIdx.x * blockDim.x + threadIdx.x;
  int stride = gridDim.x * blockDim.x;
  for (; i < n4; i += stride) {
    float4 v = reinterpret_cast<const float4*>(in)[i];
    us4 o;
    o[0] = f2b(v.x); o[1] = f2b(v.y); o[2] = f2b(v.z); o[3] = f2b(v.w);
    reinterpret_cast<us4*>(out)[i] = o;
  }
}

// ---------------- weight composition with reordered output columns ----------------
// h (t<20): C = HG[:,128:256] @ HU[128x640]. W_h2 [128x768] cols:
//   0:128=C[gH] 128:256=C[gP] 256:384=C[s(512:640)] 384:512=HG_h(direct)
//   512:640=C[deg·h(256:384)] 640:768=C[deg·p(384:512)]
// p (t>=20): C = PG[:,128:256] @ PU[128x384]. W_p2 [128x512] cols:
//   0:128=C[gP] 128:256=C[s'(256:384)] 256:384=PG_p(direct) 384:512=C[deg·p(128:256)]
__launch_bounds__(256)
__global__ void compose_w(const float* __restrict__ hg, const float* __restrict__ hu,
                          const float* __restrict__ pg, const float* __restrict__ pu,
                          const float* __restrict__ hub, const float* __restrict__ pub,
                          unsigned short* __restrict__ wh, unsigned short* __restrict__ wp,
                          float* __restrict__ bh, float* __restrict__ bp) {
  __shared__ float As[128][129];
  __shared__ float Bs[128][36];
  __shared__ float bvs[128];
  const int l = blockIdx.x >> 5, t = blockIdx.x & 31;
  const float* A; const float* B; const float* bv; unsigned short* W; float* bo;
  int lda, ldb, ldw, cbase, wbase, dbase;
  if (t < 20) {
    A = hg + (size_t)l * 128 * 256; lda = 256;
    B = hu + (size_t)l * 128 * 640; ldb = 640;
    W = wh + (size_t)l * 128 * 768; ldw = 768;
    bv = hub + l * 128; bo = bh + l * 128; cbase = t * 32;
    wbase = (cbase < 256) ? cbase : (cbase < 512 ? cbase + 256 : cbase - 256);
    dbase = 384;
  } else {
    A = pg + (size_t)l * 128 * 256; lda = 256;
    B = pu + (size_t)l * 128 * 384; ldb = 384;
    W = wp + (size_t)l * 128 * 512; ldw = 512;
    bv = pub + l * 128; bo = bp + l * 128; cbase = (t - 20) * 32;
    wbase = (cbase < 128) ? cbase : (cbase < 256 ? cbase + 256 : cbase - 128);
    dbase = 256;
  }
  const int tid = threadIdx.x;
  for (int idx = tid; idx < 128 * 128; idx += 256) {
    int r = idx >> 7, c = idx & 127;
    As[r][c] = A[r * lda + 128 + c];
  }
  for (int idx = tid; idx < 128 * 32; idx += 256) {
    int m = idx >> 5, c = idx & 31;
    Bs[m][c] = B[m * ldb + cbase + c];
  }
  if (tid < 128) bvs[tid] = bv[tid];
  __syncthreads();
  const int o = tid & 127, g = tid >> 7;
  float acc[16];
#pragma unroll
  for (int j = 0; j < 16; ++j) acc[j] = 0.f;
  for (int m = 0; m < 128; ++m) {
    float a = As[o][m];
#pragma unroll
    for (int j4 = 0; j4 < 4; ++j4) {
      float4 b4 = *reinterpret_cast<const float4*>(&Bs[m][g * 16 + j4 * 4]);
      acc[j4 * 4 + 0] += a * b4.x; acc[j4 * 4 + 1] += a * b4.y;
      acc[j4 * 4 + 2] += a * b4.z; acc[j4 * 4 + 3] += a * b4.w;
    }
  }
#pragma unroll
  for (int j4 = 0; j4 < 4; ++j4) {
    us4 ov;
    ov[0] = f2b(acc[j4 * 4 + 0]); ov[1] = f2b(acc[j4 * 4 + 1]);
    ov[2] = f2b(acc[j4 * 4 + 2]); ov[3] = f2b(acc[j4 * 4 + 3]);
    *reinterpret_cast<us4*>(&W[(long)o * ldw + wbase + g * 16 + j4 * 4]) = ov;
  }
  if (cbase == 0) {
    for (int idx = tid; idx < 128 * 128; idx += 256) {
      int oo = idx >> 7, m = idx & 127;
      W[(long)oo * ldw + dbase + m] = f2b(A[oo * lda + m]);
    }
    if (tid < 128) {
      float s = 0.f;
      for (int m = 0; m < 128; ++m) s += As[tid][m] * bvs[m];
      bo[tid] = s;
    }
  }
}

// ---------------- MFMA h-embed: out[M,0:128 of 256] = xb[M,64] @ w64[128,64]^T + b ---------
__launch_bounds__(256, 3)
__global__ void embed_mfma64(const unsigned short* __restrict__ xb, const unsigned short* __restrict__ w64,
                             const float* __restrict__ b, unsigned short* __restrict__ out, int M) {
  __shared__ __align__(16) unsigned short ldsW[2 * 8 * 64 * 8];  // 16KB, [sub][ntile][lane][8]
  const int tid = threadIdx.x;
  const int wid = tid >> 6, lane = tid & 63;
  const long rowBase = (long)blockIdx.x * 128 + wid * 32;
  const int lq = lane >> 4;
  const int lr = lane & 15;

  // stage whole W (fragment order) once
#pragma unroll
  for (int it = 0; it < 4; ++it) {
    int f = tid + it * 256;         // 0..1023
    int sub = f >> 9, r = f & 511;
    int t = r >> 6, l = r & 63;
    int n = t * 16 + (l & 15);
    int kk = sub * 32 + ((l >> 4) * 8);
    *reinterpret_cast<bf16x8*>(&ldsW[f * 8]) =
        *reinterpret_cast<const bf16x8*>(&w64[(long)n * 64 + kk]);
  }
  __syncthreads();

  int rowD[2];
#pragma unroll
  for (int am = 0; am < 2; ++am) {
    long e = rowBase + am * 16 + lr;
    if (e >= M) e = M - 1;
    rowD[am] = (int)e;
  }

  f32x4 acc[2][8];
#pragma unroll
  for (int i = 0; i < 2; ++i)
#pragma unroll
    for (int j = 0; j < 8; ++j) acc[i][j] = 0.f;

#pragma unroll
  for (int s = 0; s < 2; ++s) {
    bf16x8 a[2];
#pragma unroll
    for (int am = 0; am < 2; ++am)
      a[am] = *reinterpret_cast<const bf16x8*>(&xb[(long)rowD[am] * 64 + s * 32 + lq * 8]);
#pragma unroll
    for (int n = 0; n < 8; ++n) {
      bf16x8 bb = *reinterpret_cast<const bf16x8*>(&ldsW[((s << 9) + (n << 6) + lane) * 8]);
      acc[0][n] = __builtin_amdgcn_mfma_f32_16x16x32_bf16(a[0], bb, acc[0][n], 0, 0, 0);
      acc[1][n] = __builtin_amdgcn_mfma_f32_16x16x32_bf16(a[1], bb, acc[1][n], 0, 0, 0);
    }
  }

  float bo[8];
#pragma unroll
  for (int n = 0; n < 8; ++n) bo[n] = b[n * 16 + lr];

#pragma unroll
  for (int am = 0; am < 2; ++am) {
#pragma unroll
    for (int r = 0; r < 4; ++r) {
      long row = rowBase + am * 16 + lq * 4 + r;
      if (row < M) {
#pragma unroll
        for (int n = 0; n < 8; ++n)
          out[row * 256 + n * 16 + lr] = f2b(acc[am][n][r] + bo[n]);
      }
    }
  }
}

// ---------------- embeddings (K=16 paths): out[M,128] = in[M,K] @ w^T + (deg?)*b ----------
template<int K>
__launch_bounds__(256)
__global__ void embed_fast(const float* __restrict__ in, const float* __restrict__ w,
                           const float* __restrict__ b, unsigned short* __restrict__ out,
                           long M, int ostride, int ocoloff, const float* __restrict__ degB) {
  __shared__ float wT[K][129];
  __shared__ float xt[16 * K];
  const int tid = threadIdx.x;
  const int col = tid & 127;
  const int half = tid >> 7;
  for (int idx = tid; idx < 128 * K; idx += 256) {
    int c = idx / K, k = idx % K;
    wT[k][c] = w[idx];
  }
  __syncthreads();
  float wreg[K];
#pragma unroll
  for (int k = 0; k < K; ++k) wreg[k] = wT[k][col];
  const float bcol = b[col];

  for (long r0 = (long)blockIdx.x * 16; r0 < M; r0 += (long)gridDim.x * 16) {
    __syncthreads();
    const float4* src4 = reinterpret_cast<const float4*>(in + r0 * K);
    const int n4 = 16 * K / 4;
    if (r0 + 16 <= M) {
      for (int i = tid; i < n4; i += 256)
        reinterpret_cast<float4*>(xt)[i] = src4[i];
    } else {
      int rem = (int)((M - r0) * K) / 4;
      for (int i = tid; i < n4; i += 256) {
        float4 z = {0.f, 0.f, 0.f, 0.f};
        reinterpret_cast<float4*>(xt)[i] = (i < rem) ? src4[i] : z;
      }
    }
    __syncthreads();
#pragma unroll
    for (int rr = 0; rr < 8; ++rr) {
      long row = r0 + half * 8 + rr;
      if (row >= M) break;
      const float* xr = &xt[(half * 8 + rr) * K];
      float acc = bcol * (degB ? degB[row] : 1.0f);
#pragma unroll
      for (int k4 = 0; k4 < K / 4; ++k4) {
        float4 xv = reinterpret_cast<const float4*>(xr)[k4];
        acc += xv.x * wreg[k4 * 4] + xv.y * wreg[k4 * 4 + 1] +
               xv.z * wreg[k4 * 4 + 2] + xv.w * wreg[k4 * 4 + 3];
      }
      out[row * ostride + ocoloff + col] = f2b(acc);
    }
  }
}

// ---------------- CSR build ----------------
__global__ void count_deg(const int* __restrict__ rec, int* __restrict__ deg, int E) {
  int i = blockIdx.x * blockDim.x + threadIdx.x;
  if (i < E) atomicAdd(&deg[rec[i]], 1);
}

__global__ void scan_blk(const int* __restrict__ deg, int* __restrict__ tmp,
                         int* __restrict__ blkSum, int N) {
  __shared__ int ts[256];
  const int b = blockIdx.x, t = threadIdx.x;
  const int base = b * 1024 + t * 4;
  int v0 = (base + 0 < N) ? deg[base + 0] : 0;
  int v1 = (base + 1 < N) ? deg[base + 1] : 0;
  int v2 = (base + 2 < N) ? deg[base + 2] : 0;
  int v3 = (base + 3 < N) ? deg[base + 3] : 0;
  int tsum = v0 + v1 + v2 + v3;
  ts[t] = tsum;
  __syncthreads();
  for (int off = 1; off < 256; off <<= 1) {
    int x = (t >= off) ? ts[t - off] : 0;
    __syncthreads();
    ts[t] += x;
    __syncthreads();
  }
  int texcl = ts[t] - tsum;
  if (base + 0 < N) tmp[base + 0] = texcl;
  if (base + 1 < N) tmp[base + 1] = texcl + v0;
  if (base + 2 < N) tmp[base + 2] = texcl + v0 + v1;
  if (base + 3 < N) tmp[base + 3] = texcl + v0 + v1 + v2;
  if (t == 255) blkSum[b] = ts[255];
}

__global__ void scan_top(int* __restrict__ blkSum, int nb) {
  __shared__ int s[64];
  int t = threadIdx.x;
  if (t < nb) s[t] = blkSum[t];
  __syncthreads();
  if (t == 0) {
    int run = 0;
    for (int i = 0; i < nb; ++i) { int x = s[i]; s[i] = run; run += x; }
  }
  __syncthreads();
  if (t < nb) blkSum[t] = s[t];
}

__global__ void scan_fix(const int* __restrict__ deg, int* __restrict__ row_ptr,
                         const int* __restrict__ blkOff, int* __restrict__ cursor,
                         float* __restrict__ degF, int N, int E) {
  const int b = blockIdx.x, t = threadIdx.x;
  const int base = b * 1024 + t * 4;
  const int off = blkOff[b];
#pragma unroll
  for (int k = 0; k < 4; ++k) {
    int i = base + k;
    if (i < N) {
      int v = row_ptr[i] + off;
      row_ptr[i] = v;
      cursor[i] = v;
      degF[i] = (float)deg[i];
    }
  }
  if (b == 0 && t == 0) row_ptr[N] = E;
}

__global__ void scatter_perm(const int* __restrict__ rec, const int* __restrict__ send,
                             int* __restrict__ cursor, int* __restrict__ perm,
                             int* __restrict__ sendP, int E) {
  int i = blockIdx.x * blockDim.x + threadIdx.x;
  if (i < E) {
    int pos = atomicAdd(&cursor[rec[i]], 1);
    perm[pos] = i;
    sendP[pos] = send[i];
  }
}

// ---------------- segment-sum of raw edge features (E x 16 fp32) ----------------
__global__ void segsum_raw(const float* __restrict__ eraw, const int* __restrict__ row_ptr,
                           const int* __restrict__ perm, float* __restrict__ out16, int N) {
  int sub = threadIdx.x >> 4;
  int f = threadIdx.x & 15;
  int r = blockIdx.x * 16 + sub;
  if (r >= N) return;
  int j0 = row_ptr[r], j1 = row_ptr[r + 1];
  float s0 = 0.f, s1 = 0.f;
  int j = j0;
  for (; j + 2 <= j1; j += 2) {
    int e0 = perm[j], e1 = perm[j + 1];
    s0 += eraw[(long)e0 * 16 + f];
    s1 += eraw[(long)e1 * 16 + f];
  }
  if (j < j1) s0 += eraw[(long)perm[j] * 16 + f];
  out16[(long)r * 16 + f] = s0 + s1;
}

// ---------------- sender-gather segment sum, 256 cols (4-deep ILP) ----------------
__launch_bounds__(256)
__global__ void gather_sum256(const unsigned short* __restrict__ src,
                              const int* __restrict__ row_ptr, const int* __restrict__ sendP,
                              unsigned short* __restrict__ dst, int N) {
  const int wid = threadIdx.x >> 6, lane = threadIdx.x & 63;
  const int r = blockIdx.x * 4 + wid;
  if (r >= N) return;
  const int j0 = row_ptr[r], j1 = row_ptr[r + 1];
  const int off = lane * 4;
  float a0 = 0.f, a1 = 0.f, a2 = 0.f, a3 = 0.f;
  int j = j0;
  for (; j + 4 <= j1; j += 4) {
    int i0 = sendP[j], i1 = sendP[j + 1], i2 = sendP[j + 2], i3 = sendP[j + 3];
    us4 x = *reinterpret_cast<const us4*>(&src[(long)i0 * 256 + off]);
    us4 y = *reinterpret_cast<const us4*>(&src[(long)i1 * 256 + off]);
    us4 z = *reinterpret_cast<const us4*>(&src[(long)i2 * 256 + off]);
    us4 w = *reinterpret_cast<const us4*>(&src[(long)i3 * 256 + off]);
    a0 += b2f(x[0]) + b2f(y[0]) + b2f(z[0]) + b2f(w[0]);
    a1 += b2f(x[1]) + b2f(y[1]) + b2f(z[1]) + b2f(w[1]);
    a2 += b2f(x[2]) + b2f(y[2]) + b2f(z[2]) + b2f(w[2]);
    a3 += b2f(x[3]) + b2f(y[3]) + b2f(z[3]) + b2f(w[3]);
  }
  for (; j < j1; ++j) {
    us4 x = *reinterpret_cast<const us4*>(&src[(long)sendP[j] * 256 + off]);
    a0 += b2f(x[0]); a1 += b2f(x[1]); a2 += b2f(x[2]); a3 += b2f(x[3]);
  }
  us4 o;
  o[0] = f2b(a0); o[1] = f2b(a1); o[2] = f2b(a2); o[3] = f2b(a3);
  *reinterpret_cast<us4*>(&dst[(long)r * 256 + off]) = o;
}

// ---------------- sender-gather segment sum, 128 cols, 2 edges/wave-pass, 4-deep ILP --------
__launch_bounds__(256)
__global__ void gather_sum128(const unsigned short* __restrict__ src, int col,
                              const int* __restrict__ row_ptr, const int* __restrict__ sendP,
                              unsigned short* __restrict__ dst, int N) {
  const int wid = threadIdx.x >> 6, lane = threadIdx.x & 63;
  const int r = blockIdx.x * 4 + wid;
  if (r >= N) return;
  const int j0 = row_ptr[r], j1 = row_ptr[r + 1];
  const int half = lane >> 5;
  const int c = lane & 31;
  const int off = col + c * 4;
  float a0 = 0.f, a1 = 0.f, a2 = 0.f, a3 = 0.f;
  float b0 = 0.f, b1 = 0.f, b2 = 0.f, b3 = 0.f;
  int j = j0 + half;
  for (; j + 6 < j1; j += 8) {  // four independent load chains per lane
    int i0 = sendP[j], i1 = sendP[j + 2], i2 = sendP[j + 4], i3 = sendP[j + 6];
    us4 x = *reinterpret_cast<const us4*>(&src[(long)i0 * 256 + off]);
    us4 y = *reinterpret_cast<const us4*>(&src[(long)i1 * 256 + off]);
    us4 z = *reinterpret_cast<const us4*>(&src[(long)i2 * 256 + off]);
    us4 w = *reinterpret_cast<const us4*>(&src[(long)i3 * 256 + off]);
    a0 += b2f(x[0]) + b2f(z[0]); a1 += b2f(x[1]) + b2f(z[1]);
    a2 += b2f(x[2]) + b2f(z[2]); a3 += b2f(x[3]) + b2f(z[3]);
    b0 += b2f(y[0]) + b2f(w[0]); b1 += b2f(y[1]) + b2f(w[1]);
    b2 += b2f(y[2]) + b2f(w[2]); b3 += b2f(y[3]) + b2f(w[3]);
  }
  for (; j + 2 < j1; j += 4) {
    int i0 = sendP[j], i1 = sendP[j + 2];
    us4 x = *reinterpret_cast<const us4*>(&src[(long)i0 * 256 + off]);
    us4 y = *reinterpret_cast<const us4*>(&src[(long)i1 * 256 + off]);
    a0 += b2f(x[0]); a1 += b2f(x[1]); a2 += b2f(x[2]); a3 += b2f(x[3]);
    b0 += b2f(y[0]); b1 += b2f(y[1]); b2 += b2f(y[2]); b3 += b2f(y[3]);
  }
  if (j < j1) {
    us4 x = *reinterpret_cast<const us4*>(&src[(long)sendP[j] * 256 + off]);
    a0 += b2f(x[0]); a1 += b2f(x[1]); a2 += b2f(x[2]); a3 += b2f(x[3]);
  }
  a0 += b0; a1 += b1; a2 += b2; a3 += b3;
  a0 += __shfl_xor(a0, 32); a1 += __shfl_xor(a1, 32);
  a2 += __shfl_xor(a2, 32); a3 += __shfl_xor(a3, 32);
  if (half == 0) {
    us4 o;
    o[0] = f2b(a0); o[1] = f2b(a1); o[2] = f2b(a2); o[3] = f2b(a3);
    *reinterpret_cast<us4*>(&dst[(long)r * 256 + off]) = o;
  }
}

// ---------------- node-level multi-section MFMA GEMM, software-pipelined (1 barrier/chunk) --
// Per-section nibbles: srcsel (0=sp0 stride256, 1=sp1 stride256, 2=sp2 stride128),
// coloffs (x128), sflags (0=plain; 1=dual: plain + deg-scaled; 2=scaled-only).
// Kw = total W columns. v = acc + bdeg[n]*deg[row] + bone[n].
// Pipeline per 32-col chunk: issue W loads -> compute prev chunk -> ds_write -> 1 barrier.
__launch_bounds__(256, 3)
__global__ void gemm_mp(int M, int nsrc, int Kw, int srcsel, int coloffs, int sflags,
                        const unsigned short* __restrict__ sp0, const unsigned short* __restrict__ sp1,
                        const unsigned short* __restrict__ sp2,
                        const unsigned short* __restrict__ Wb,
                        const float* __restrict__ bdeg, const float* __restrict__ bone,
                        const float* __restrict__ degF,
                        unsigned short* __restrict__ outB, int ostride, int ocoloff,
                        float* __restrict__ outF) {
  __shared__ __align__(16) unsigned short ldsW[2 * 8 * 64 * 8];  // 2 x 8KB ping-pong
  const int tid = threadIdx.x;
  const int lane = tid & 63;
  const long rowBase = (long)blockIdx.x * 128 + (tid >> 6) * 32;
  const int lq = lane >> 4;
  const int lr = lane & 15;

  int rowD[2];
  float degD[2];
#pragma unroll
  for (int am = 0; am < 2; ++am) {
    long e = rowBase + am * 16 + lr;
    if (e >= M) e = M - 1;
    rowD[am] = (int)e;
    degD[am] = degF[rowD[am]];
  }

  f32x4 acc[2][8];
#pragma unroll
  for (int i = 0; i < 2; ++i)
#pragma unroll
    for (int j = 0; j < 8; ++j) acc[i][j] = 0.f;

  // staging address pattern (constant per thread): thread stages rows n0/n1 at col-sub kq
  const int st_t0 = tid >> 6, st_l = tid & 63;
  const int st_n0 = st_t0 * 16 + (st_l & 15);
  const int st_n1 = st_n0 + 64;
  const int st_kq = (st_l >> 4) * 8;

  bf16x8 pa0, pa1;         // previous chunk's (scaled) A fragments
  int pbase = 0;           // previous chunk's LDS base (in shorts)
  int havePrev = 0;
  int parity = 0;

  int wcol = 0;
  for (int si = 0; si < nsrc; ++si) {
    const int sel = (srcsel >> (si * 4)) & 15;
    const unsigned short* sp = (sel == 0) ? sp0 : (sel == 1) ? sp1 : sp2;
    const long astride = (sel == 2) ? 128 : 256;
    const int acoloff = ((coloffs >> (si * 4)) & 15) * 128;
    const int f = (sflags >> (si * 4)) & 15;
    const int nrep = (f == 1) ? 2 : 1;
    for (int sub = 0; sub < 4; ++sub) {
      const int koff = acoloff + sub * 32 + lq * 8;
      bf16x8 a0 = *reinterpret_cast<const bf16x8*>(&sp[(long)rowD[0] * astride + koff]);
      bf16x8 a1 = *reinterpret_cast<const bf16x8*>(&sp[(long)rowD[1] * astride + koff]);
      for (int rep = 0; rep < nrep; ++rep) {
        const bool sc = (f == 2) || (rep == 1);
        const int wk = wcol + rep * 128 + sub * 32;
        // issue W global loads for THIS chunk (overlap with prev compute)
        bf16x8 w0 = *reinterpret_cast<const bf16x8*>(&Wb[(long)st_n0 * Kw + wk + st_kq]);
        bf16x8 w1 = *reinterpret_cast<const bf16x8*>(&Wb[(long)st_n1 * Kw + wk + st_kq]);
        // compute previous chunk
        if (havePrev) {
#pragma unroll
          for (int n = 0; n < 8; ++n) {
            bf16x8 b = *reinterpret_cast<const bf16x8*>(&ldsW[pbase + ((n << 6) + lane) * 8]);
            acc[0][n] = __builtin_amdgcn_mfma_f32_16x16x32_bf16(pa0, b, acc[0][n], 0, 0, 0);
            acc[1][n] = __builtin_amdgcn_mfma_f32_16x16x32_bf16(pa1, b, acc[1][n], 0, 0, 0);
          }
        }
        // write this chunk into ping-pong buffer, single barrier
        const int base = parity * (8 * 64 * 8);
        *reinterpret_cast<bf16x8*>(&ldsW[base + tid * 8]) = w0;
        *reinterpret_cast<bf16x8*>(&ldsW[base + (tid + 256) * 8]) = w1;
        __syncthreads();
        pa0 = sc ? scale8(a0, degD[0]) : a0;
        pa1 = sc ? scale8(a1, degD[1]) : a1;
        pbase = base;
        parity ^= 1;
        havePrev = 1;
      }
    }
    wcol += nrep * 128;
  }
  // epilogue: compute the last chunk
#pragma unroll
  for (int n = 0; n < 8; ++n) {
    bf16x8 b = *reinterpret_cast<const bf16x8*>(&ldsW[pbase + ((n << 6) + lane) * 8]);
    acc[0][n] = __builtin_amdgcn_mfma_f32_16x16x32_bf16(pa0, b, acc[0][n], 0, 0, 0);
    acc[1][n] = __builtin_amdgcn_mfma_f32_16x16x32_bf16(pa1, b, acc[1][n], 0, 0, 0);
  }

  float bd[8], bo[8];
#pragma unroll
  for (int n = 0; n < 8; ++n) {
    bd[n] = bdeg ? bdeg[n * 16 + lr] : 0.f;
    bo[n] = bone ? bone[n * 16 + lr] : 0.f;
  }

  // C layout (16x16x32 bf16): col = lane&15, row = (lane>>4)*4 + reg
#pragma unroll
  for (int am = 0; am < 2; ++am) {
#pragma unroll
    for (int r = 0; r < 4; ++r) {
      long row = rowBase + am * 16 + lq * 4 + r;
      if (row < M) {
        float d = degF[row];
        long ob = row * ostride + ocoloff;
#pragma unroll
        for (int n = 0; n < 8; ++n) {
          float v = acc[am][n][r] + bd[n] * d + bo[n];
          outB[ob + n * 16 + lr] = f2b(v);
          if (outF) outF[row * 128 + n * 16 + lr] = v;
        }
      }
    }
  }
}

// ---------------- per-graph aggregation v2: wave-per-32-row slab, us4 loads ----------------
__launch_bounds__(256)
__global__ void readout_agg(const unsigned short* __restrict__ hp,
                            const int* __restrict__ batch, float* __restrict__ hep, int N) {
  const int wid = threadIdx.x >> 6, lane = threadIdx.x & 63;
  const int n0 = blockIdx.x * 128 + wid * 32;
  if (n0 >= N) return;
  int n1 = n0 + 32; if (n1 > N) n1 = N;
  const int off = lane * 4;
  float s0 = 0.f, s1 = 0.f, s2 = 0.f, s3 = 0.f;
  int curg = -1;
  for (int n = n0; n < n1; ++n) {
    int g = batch[n];
    if (g != curg) {
      if (curg >= 0) {
        float* dst = &hep[(long)curg * 256 + off];
        unsafeAtomicAdd(dst + 0, s0); unsafeAtomicAdd(dst + 1, s1);
        unsafeAtomicAdd(dst + 2, s2); unsafeAtomicAdd(dst + 3, s3);
      }
      curg = g; s0 = s1 = s2 = s3 = 0.f;
    }
    us4 v = *reinterpret_cast<const us4*>(&hp[(long)n * 256 + off]);
    s0 += b2f(v[0]); s1 += b2f(v[1]); s2 += b2f(v[2]); s3 += b2f(v[3]);
  }
  if (curg >= 0) {
    float* dst = &hep[(long)curg * 256 + off];
    unsafeAtomicAdd(dst + 0, s0); unsafeAtomicAdd(dst + 1, s1);
    unsafeAtomicAdd(dst + 2, s2); unsafeAtomicAdd(dst + 3, s3);
  }
}

// ---------------- readout MLP: one block per graph ----------------
__global__ void mlp_kernel(const float* __restrict__ hep,
                           const float* __restrict__ r1w, const float* __restrict__ r1b,
                           const float* __restrict__ r2w, const float* __restrict__ r2b,
                           const float* __restrict__ r3w, const float* __restrict__ r3b,
                           float* __restrict__ out) {
  int g = blockIdx.x, t = threadIdx.x;  // 128 threads
  __shared__ float x[256];
  __shared__ float y[128];
  __shared__ float z[64];
  x[t] = hep[(long)g * 256 + t];
  x[t + 128] = hep[(long)g * 256 + 128 + t];
  __syncthreads();
  float s = r1b[t];
  for (int k = 0; k < 256; ++k) s += r1w[t * 256 + k] * x[k];
  y[t] = fmaxf(s, 0.f);
  __syncthreads();
  if (t < 64) {
    float s2 = r2b[t];
    for (int k = 0; k < 128; ++k) s2 += r2w[t * 128 + k] * y[k];
    z[t] = fmaxf(s2, 0.f);
  }
  __syncthreads();
  if (t == 0) {
    float s3 = r3b[0];
    for (int k = 0; k < 64; ++k) s3 += r3w[k] * z[k];
    out[g] = s3;
  }
}

extern "C" void kernel_launch(void* const* d_in, const int* in_sizes, int n_in,
                              void* d_out, int out_size, void* d_ws, size_t ws_size,
                              hipStream_t stream) {
  const float* h_in = (const float*)d_in[0];
  const float* e_in = (const float*)d_in[1];
  const float* p_in = (const float*)d_in[2];
  const int* ei = (const int*)d_in[3];
  const int* batch = (const int*)d_in[4];
  const float* he_w = (const float*)d_in[5];  const float* he_b = (const float*)d_in[6];
  const float* ee_w = (const float*)d_in[7];  const float* ee_b = (const float*)d_in[8];
  const float* pe_w = (const float*)d_in[9];  const float* pe_b = (const float*)d_in[10];
  const float* hu_w = (const float*)d_in[11]; const float* hu_b = (const float*)d_in[12];
  const float* eu_w = (const float*)d_in[13]; const float* eu_b = (const float*)d_in[14];
  const float* pu_w = (const float*)d_in[15]; const float* pu_b = (const float*)d_in[16];
  const float* hg_w = (const float*)d_in[17]; const float* hg_b = (const float*)d_in[18];
  const float* pg_w = (const float*)d_in[19]; const float* pg_b = (const float*)d_in[20];
  const float* r1w = (const float*)d_in[21];  const float* r1b = (const float*)d_in[22];
  const float* r2w = (const float*)d_in[23];  const float* r2b = (const float*)d_in[24];
  const float* r3w = (const float*)d_in[25];  const float* r3b = (const float*)d_in[26];

  const int N = 50000, E = 400000, G = 256;
  const int* send = ei;
  const int* rec = ei + E;

  char* ws = (char*)d_ws;
  size_t off = 0;
  auto alloc = [&](size_t bytes) {
    void* pp = ws + off;
    off += (bytes + 255) & ~(size_t)255;
    return pp;
  };
  unsigned short* hp  = (unsigned short*)alloc((size_t)N * 256 * 2);  // [h|p]
  unsigned short* gHP = (unsigned short*)alloc((size_t)N * 256 * 2);  // [sum h[send] | sum p[send]]
  unsigned short* sT  = (unsigned short*)alloc((size_t)N * 128 * 2);  // s = sum_in e
  unsigned short* hb16 = (unsigned short*)alloc((size_t)N * 64 * 2);  // h_in as bf16
  unsigned short* w_he = (unsigned short*)alloc((size_t)128 * 64 * 2);
  float* segsumF = (float*)alloc((size_t)N * 16 * 4);
  int* deg = (int*)alloc((size_t)N * 4);
  int* row_ptr = (int*)alloc((size_t)(N + 1) * 4);
  int* cursor = (int*)alloc((size_t)N * 4);
  int* blkSum = (int*)alloc((size_t)64 * 4);
  int* perm = (int*)alloc((size_t)E * 4);
  int* sendP = (int*)alloc((size_t)E * 4);
  float* degF = (float*)alloc((size_t)N * 4);
  float* hep = (float*)alloc((size_t)G * 256 * 4);
  unsigned short* w_h2 = (unsigned short*)alloc((size_t)4 * 128 * 768 * 2);  // reordered composed
  unsigned short* w_p2 = (unsigned short*)alloc((size_t)4 * 128 * 512 * 2);  // reordered composed
  unsigned short* w_eu = (unsigned short*)alloc((size_t)4 * 128 * 384 * 2);
  float* bh1 = (float*)alloc((size_t)4 * 128 * 4);  // HG_m @ hu_b
  float* bp1 = (float*)alloc((size_t)4 * 128 * 4);  // PG_m @ pu_b
  (void)ws_size; (void)n_in; (void)in_sizes; (void)out_size;

  // conversions + composed weights
  f2b_kernel<<<192, 256, 0, stream>>>(eu_w, w_eu, 4 * 128 * 384 / 4);
  f2b_kernel<<<2048, 256, 0, stream>>>(h_in, hb16, N * 64 / 4);
  f2b_kernel<<<8, 256, 0, stream>>>(he_w, w_he, 128 * 64 / 4);
  compose_w<<<128, 256, 0, stream>>>(hg_w, hu_w, pg_w, pu_w, hu_b, pu_b, w_h2, w_p2, bh1, bp1);

  // CSR by rec (+ pre-permuted sender index); hierarchical scan
  const int nb = (N + 1023) / 1024;  // 49
  hipMemsetAsync(deg, 0, (size_t)N * 4, stream);
  count_deg<<<(E + 255) / 256, 256, 0, stream>>>(rec, deg, E);
  scan_blk<<<nb, 256, 0, stream>>>(deg, row_ptr, blkSum, N);
  scan_top<<<1, 64, 0, stream>>>(blkSum, nb);
  scan_fix<<<nb, 256, 0, stream>>>(deg, row_ptr, blkSum, cursor, degF, N, E);
  scatter_perm<<<(E + 255) / 256, 256, 0, stream>>>(rec, send, cursor, perm, sendP, E);

  // embeddings
  embed_mfma64<<<(N + 127) / 128, 256, 0, stream>>>(hb16, w_he, he_b, hp, N);
  embed_fast<16><<<3125, 256, 0, stream>>>(p_in, pe_w, pe_b, hp, N, 256, 128, nullptr);
  // s_0 = ee_w @ (sum_in e_raw) + deg*ee_b   (e stays virtual forever)
  segsum_raw<<<(N + 15) / 16, 256, 0, stream>>>(e_in, row_ptr, perm, segsumF, N);
  embed_fast<16><<<3125, 256, 0, stream>>>(segsumF, ee_w, ee_b, sT, N, 128, 0, degF);

  // initial sender-gather of [h|p]
  gather_sum256<<<(N + 3) / 4, 256, 0, stream>>>(hp, row_ptr, sendP, gHP, N);

  float* pOut = (float*)d_out + 256;
  const int gridN = (N + 127) / 128;  // 391
  const int gridG = (N + 3) / 4;      // 12500

  for (int l = 0; l < 4; ++l) {
    // h' = W_h2 @ [gH, gP, s, h(+deg·h), deg·p] + deg*bh1 + hg_b  (in-place)
    gemm_mp<<<gridN, 256, 0, stream>>>(N, 5, 768, 0x11200, 0x10010, 0x21000,
        gHP, hp, sT,
        w_h2 + (size_t)l * 128 * 768, bh1 + l * 128, hg_b + l * 128, degF,
        hp, 256, 0, nullptr);
    // gH' = Σ h'[send]
    gather_sum128<<<gridG, 256, 0, stream>>>(hp, 0, row_ptr, sendP, gHP, N);
    // s' = EU @ [gH', deg·h', s] + deg*eu_b
    gemm_mp<<<gridN, 256, 0, stream>>>(N, 3, 384, 0x210, 0x000, 0x020,
        gHP, hp, sT,
        w_eu + (size_t)l * 128 * 384, eu_b + l * 128, nullptr, degF,
        sT, 128, 0, nullptr);
    // p' = W_p2 @ [gP, s', p(+deg·p)] + deg*bp1 + pg_b  (in-place; last layer -> fp32 out)
    gemm_mp<<<gridN, 256, 0, stream>>>(N, 3, 512, 0x120, 0x101, 0x100,
        gHP, hp, sT,
        w_p2 + (size_t)l * 128 * 512, bp1 + l * 128, pg_b + l * 128, degF,
        hp, 256, 128, (l == 3) ? pOut : nullptr);
    // gP' = Σ p'[send]  (not needed after last layer)
    if (l < 3)
      gather_sum128<<<gridG, 256, 0, stream>>>(hp, 128, row_ptr, sendP, gHP, N);
  }

  hipMemsetAsync(hep, 0, (size_t)G * 256 * 4, stream);
  readout_agg<<<(N + 127) / 128, 256, 0, stream>>>(hp, batch, hep, N);
  mlp_kernel<<<G, 128, 0, stream>>>(hep, r1w, r1b, r2w, r2b, r3w, r3b, (float*)d_out);
}

// Round 16
// 632.807 us; speedup vs baseline: 1.0046x; 1.0046x over previous
//
#include <hip/hip_runtime.h>

typedef __attribute__((ext_vector_type(8))) short bf16x8;
typedef __attribute__((ext_vector_type(4))) float f32x4;
typedef __attribute__((ext_vector_type(4))) unsigned short us4;

__device__ __forceinline__ float b2f(unsigned short h) {
  union { unsigned int u; float f; } v; v.u = ((unsigned int)h) << 16; return v.f;
}
__device__ __forceinline__ unsigned short f2b(float f) {
  union { float f; unsigned int u; } v; v.f = f;
  unsigned int r = v.u + 0x7fffu + ((v.u >> 16) & 1u);
  return (unsigned short)(r >> 16);
}

// scale a bf16x8 A-fragment by a per-lane scalar (round-half-up — cheap)
__device__ __forceinline__ bf16x8 scale8(bf16x8 a, float d) {
  bf16x8 r;
#pragma unroll
  for (int i = 0; i < 8; ++i) {
    union { unsigned int u; float f; } v;
    v.u = ((unsigned int)(unsigned short)a[i]) << 16;
    v.f *= d;
    r[i] = (short)((v.u + 0x8000u) >> 16);
  }
  return r;
}

// ---------------- fp32 -> bf16 bulk convert ----------------
__global__ void f2b_kernel(const float* __restrict__ in, unsigned short* __restrict__ out, int n4) {
  int i = blockIdx.x * blockDim.x + threadIdx.x;
  int stride = gridDim.x * blockDim.x;
  for (; i < n4; i += stride) {
    float4 v = reinterpret_cast<const float4*>(in)[i];
    us4 o;
    o[0] = f2b(v.x); o[1] = f2b(v.y); o[2] = f2b(v.z); o[3] = f2b(v.w);
    reinterpret_cast<us4*>(out)[i] = o;
  }
}

// ---------------- fp32 [M,16] -> bf16 [M,32] zero-padded ----------------
__global__ void f2b_pad32(const float* __restrict__ in, unsigned short* __restrict__ out, long M) {
  long total = M * 8;  // us4 units of output (32 cols = 8 quads)
  long i = (long)blockIdx.x * blockDim.x + threadIdx.x;
  long stride = (long)gridDim.x * blockDim.x;
  for (; i < total; i += stride) {
    long row = i >> 3;
    int q = (int)(i & 7);
    us4 o;
    if (q < 4) {
      float4 v = *reinterpret_cast<const float4*>(&in[row * 16 + q * 4]);
      o[0] = f2b(v.x); o[1] = f2b(v.y); o[2] = f2b(v.z); o[3] = f2b(v.w);
    } else {
      o[0] = 0; o[1] = 0; o[2] = 0; o[3] = 0;
    }
    reinterpret_cast<us4*>(out)[i] = o;
  }
}

// ---------------- weight composition with reordered output columns ----------------
__launch_bounds__(256)
__global__ void compose_w(const float* __restrict__ hg, const float* __restrict__ hu,
                          const float* __restrict__ pg, const float* __restrict__ pu,
                          const float* __restrict__ hub, const float* __restrict__ pub,
                          unsigned short* __restrict__ wh, unsigned short* __restrict__ wp,
                          float* __restrict__ bh, float* __restrict__ bp) {
  __shared__ float As[128][129];
  __shared__ float Bs[128][36];
  __shared__ float bvs[128];
  const int l = blockIdx.x >> 5, t = blockIdx.x & 31;
  const float* A; const float* B; const float* bv; unsigned short* W; float* bo;
  int lda, ldb, ldw, cbase, wbase, dbase;
  if (t < 20) {
    A = hg + (size_t)l * 128 * 256; lda = 256;
    B = hu + (size_t)l * 128 * 640; ldb = 640;
    W = wh + (size_t)l * 128 * 768; ldw = 768;
    bv = hub + l * 128; bo = bh + l * 128; cbase = t * 32;
    wbase = (cbase < 256) ? cbase : (cbase < 512 ? cbase + 256 : cbase - 256);
    dbase = 384;
  } else {
    A = pg + (size_t)l * 128 * 256; lda = 256;
    B = pu + (size_t)l * 128 * 384; ldb = 384;
    W = wp + (size_t)l * 128 * 512; ldw = 512;
    bv = pub + l * 128; bo = bp + l * 128; cbase = (t - 20) * 32;
    wbase = (cbase < 128) ? cbase : (cbase < 256 ? cbase + 256 : cbase - 128);
    dbase = 256;
  }
  const int tid = threadIdx.x;
  for (int idx = tid; idx < 128 * 128; idx += 256) {
    int r = idx >> 7, c = idx & 127;
    As[r][c] = A[r * lda + 128 + c];
  }
  for (int idx = tid; idx < 128 * 32; idx += 256) {
    int m = idx >> 5, c = idx & 31;
    Bs[m][c] = B[m * ldb + cbase + c];
  }
  if (tid < 128) bvs[tid] = bv[tid];
  __syncthreads();
  const int o = tid & 127, g = tid >> 7;
  float acc[16];
#pragma unroll
  for (int j = 0; j < 16; ++j) acc[j] = 0.f;
  for (int m = 0; m < 128; ++m) {
    float a = As[o][m];
#pragma unroll
    for (int j4 = 0; j4 < 4; ++j4) {
      float4 b4 = *reinterpret_cast<const float4*>(&Bs[m][g * 16 + j4 * 4]);
      acc[j4 * 4 + 0] += a * b4.x; acc[j4 * 4 + 1] += a * b4.y;
      acc[j4 * 4 + 2] += a * b4.z; acc[j4 * 4 + 3] += a * b4.w;
    }
  }
#pragma unroll
  for (int j4 = 0; j4 < 4; ++j4) {
    us4 ov;
    ov[0] = f2b(acc[j4 * 4 + 0]); ov[1] = f2b(acc[j4 * 4 + 1]);
    ov[2] = f2b(acc[j4 * 4 + 2]); ov[3] = f2b(acc[j4 * 4 + 3]);
    *reinterpret_cast<us4*>(&W[(long)o * ldw + wbase + g * 16 + j4 * 4]) = ov;
  }
  if (cbase == 0) {
    for (int idx = tid; idx < 128 * 128; idx += 256) {
      int oo = idx >> 7, m = idx & 127;
      W[(long)oo * ldw + dbase + m] = f2b(A[oo * lda + m]);
    }
    if (tid < 128) {
      float s = 0.f;
      for (int m = 0; m < 128; ++m) s += As[tid][m] * bvs[m];
      bo[tid] = s;
    }
  }
}

// ---------------- MFMA h-embed: out[M,0:128 of 256] = xb[M,64] @ w64[128,64]^T + b ---------
__launch_bounds__(256, 3)
__global__ void embed_mfma64(const unsigned short* __restrict__ xb, const unsigned short* __restrict__ w64,
                             const float* __restrict__ b, unsigned short* __restrict__ out, int M) {
  __shared__ __align__(16) unsigned short ldsW[2 * 8 * 64 * 8];  // 16KB
  const int tid = threadIdx.x;
  const int wid = tid >> 6, lane = tid & 63;
  const long rowBase = (long)blockIdx.x * 128 + wid * 32;
  const int lq = lane >> 4;
  const int lr = lane & 15;

#pragma unroll
  for (int it = 0; it < 4; ++it) {
    int f = tid + it * 256;
    int sub = f >> 9, r = f & 511;
    int t = r >> 6, l = r & 63;
    int n = t * 16 + (l & 15);
    int kk = sub * 32 + ((l >> 4) * 8);
    *reinterpret_cast<bf16x8*>(&ldsW[f * 8]) =
        *reinterpret_cast<const bf16x8*>(&w64[(long)n * 64 + kk]);
  }
  __syncthreads();

  int rowD[2];
#pragma unroll
  for (int am = 0; am < 2; ++am) {
    long e = rowBase + am * 16 + lr;
    if (e >= M) e = M - 1;
    rowD[am] = (int)e;
  }

  f32x4 acc[2][8];
#pragma unroll
  for (int i = 0; i < 2; ++i)
#pragma unroll
    for (int j = 0; j < 8; ++j) acc[i][j] = 0.f;

#pragma unroll
  for (int s = 0; s < 2; ++s) {
    bf16x8 a[2];
#pragma unroll
    for (int am = 0; am < 2; ++am)
      a[am] = *reinterpret_cast<const bf16x8*>(&xb[(long)rowD[am] * 64 + s * 32 + lq * 8]);
#pragma unroll
    for (int n = 0; n < 8; ++n) {
      bf16x8 bb = *reinterpret_cast<const bf16x8*>(&ldsW[((s << 9) + (n << 6) + lane) * 8]);
      acc[0][n] = __builtin_amdgcn_mfma_f32_16x16x32_bf16(a[0], bb, acc[0][n], 0, 0, 0);
      acc[1][n] = __builtin_amdgcn_mfma_f32_16x16x32_bf16(a[1], bb, acc[1][n], 0, 0, 0);
    }
  }

  float bo[8];
#pragma unroll
  for (int n = 0; n < 8; ++n) bo[n] = b[n * 16 + lr];

#pragma unroll
  for (int am = 0; am < 2; ++am) {
#pragma unroll
    for (int r = 0; r < 4; ++r) {
      long row = rowBase + am * 16 + lq * 4 + r;
      if (row < M) {
#pragma unroll
        for (int n = 0; n < 8; ++n)
          out[row * 256 + n * 16 + lr] = f2b(acc[am][n][r] + bo[n]);
      }
    }
  }
}

// ---------------- MFMA K=32 embed: out[M,ocoloff+0:128] = xb32[M,32] @ w32[128,32]^T + (deg?)*b
__launch_bounds__(256, 3)
__global__ void embed_mfma32(const unsigned short* __restrict__ xb32, const unsigned short* __restrict__ w32,
                             const float* __restrict__ b, unsigned short* __restrict__ out,
                             int M, int ostride, int ocoloff, const float* __restrict__ degB) {
  __shared__ __align__(16) unsigned short ldsW[8 * 64 * 8];  // 8KB
  const int tid = threadIdx.x;
  const int wid = tid >> 6, lane = tid & 63;
  const long rowBase = (long)blockIdx.x * 128 + wid * 32;
  const int lq = lane >> 4;
  const int lr = lane & 15;

#pragma unroll
  for (int it = 0; it < 2; ++it) {
    int f = tid + it * 256;          // 0..511
    int t = f >> 6, l = f & 63;
    int n = t * 16 + (l & 15);
    int kk = (l >> 4) * 8;
    *reinterpret_cast<bf16x8*>(&ldsW[f * 8]) =
        *reinterpret_cast<const bf16x8*>(&w32[(long)n * 32 + kk]);
  }
  __syncthreads();

  int rowD[2];
#pragma unroll
  for (int am = 0; am < 2; ++am) {
    long e = rowBase + am * 16 + lr;
    if (e >= M) e = M - 1;
    rowD[am] = (int)e;
  }

  f32x4 acc[2][8];
#pragma unroll
  for (int i = 0; i < 2; ++i)
#pragma unroll
    for (int j = 0; j < 8; ++j) acc[i][j] = 0.f;

  bf16x8 a0 = *reinterpret_cast<const bf16x8*>(&xb32[(long)rowD[0] * 32 + lq * 8]);
  bf16x8 a1 = *reinterpret_cast<const bf16x8*>(&xb32[(long)rowD[1] * 32 + lq * 8]);
#pragma unroll
  for (int n = 0; n < 8; ++n) {
    bf16x8 bb = *reinterpret_cast<const bf16x8*>(&ldsW[((n << 6) + lane) * 8]);
    acc[0][n] = __builtin_amdgcn_mfma_f32_16x16x32_bf16(a0, bb, acc[0][n], 0, 0, 0);
    acc[1][n] = __builtin_amdgcn_mfma_f32_16x16x32_bf16(a1, bb, acc[1][n], 0, 0, 0);
  }

  float bo[8];
#pragma unroll
  for (int n = 0; n < 8; ++n) bo[n] = b[n * 16 + lr];

#pragma unroll
  for (int am = 0; am < 2; ++am) {
#pragma unroll
    for (int r = 0; r < 4; ++r) {
      long row = rowBase + am * 16 + lq * 4 + r;
      if (row < M) {
        float bs = degB ? degB[row] : 1.0f;
        long ob = row * ostride + ocoloff;
#pragma unroll
        for (int n = 0; n < 8; ++n)
          out[ob + n * 16 + lr] = f2b(acc[am][n][r] + bo[n] * bs);
      }
    }
  }
}

// ---------------- CSR build ----------------
__global__ void count_deg(const int* __restrict__ rec, int* __restrict__ deg, int E) {
  int i = blockIdx.x * blockDim.x + threadIdx.x;
  if (i < E) atomicAdd(&deg[rec[i]], 1);
}

__global__ void scan_blk(const int* __restrict__ deg, int* __restrict__ tmp,
                         int* __restrict__ blkSum, int N) {
  __shared__ int ts[256];
  const int b = blockIdx.x, t = threadIdx.x;
  const int base = b * 1024 + t * 4;
  int v0 = (base + 0 < N) ? deg[base + 0] : 0;
  int v1 = (base + 1 < N) ? deg[base + 1] : 0;
  int v2 = (base + 2 < N) ? deg[base + 2] : 0;
  int v3 = (base + 3 < N) ? deg[base + 3] : 0;
  int tsum = v0 + v1 + v2 + v3;
  ts[t] = tsum;
  __syncthreads();
  for (int off = 1; off < 256; off <<= 1) {
    int x = (t >= off) ? ts[t - off] : 0;
    __syncthreads();
    ts[t] += x;
    __syncthreads();
  }
  int texcl = ts[t] - tsum;
  if (base + 0 < N) tmp[base + 0] = texcl;
  if (base + 1 < N) tmp[base + 1] = texcl + v0;
  if (base + 2 < N) tmp[base + 2] = texcl + v0 + v1;
  if (base + 3 < N) tmp[base + 3] = texcl + v0 + v1 + v2;
  if (t == 255) blkSum[b] = ts[255];
}

__global__ void scan_top(int* __restrict__ blkSum, int nb) {
  __shared__ int s[64];
  int t = threadIdx.x;
  if (t < nb) s[t] = blkSum[t];
  __syncthreads();
  if (t == 0) {
    int run = 0;
    for (int i = 0; i < nb; ++i) { int x = s[i]; s[i] = run; run += x; }
  }
  __syncthreads();
  if (t < nb) blkSum[t] = s[t];
}

__global__ void scan_fix(const int* __restrict__ deg, int* __restrict__ row_ptr,
                         const int* __restrict__ blkOff, int* __restrict__ cursor,
                         float* __restrict__ degF, int N, int E) {
  const int b = blockIdx.x, t = threadIdx.x;
  const int base = b * 1024 + t * 4;
  const int off = blkOff[b];
#pragma unroll
  for (int k = 0; k < 4; ++k) {
    int i = base + k;
    if (i < N) {
      int v = row_ptr[i] + off;
      row_ptr[i] = v;
      cursor[i] = v;
      degF[i] = (float)deg[i];
    }
  }
  if (b == 0 && t == 0) row_ptr[N] = E;
}

__global__ void scatter_perm(const int* __restrict__ rec, const int* __restrict__ send,
                             int* __restrict__ cursor, int* __restrict__ perm,
                             int* __restrict__ sendP, int E) {
  int i = blockIdx.x * blockDim.x + threadIdx.x;
  if (i < E) {
    int pos = atomicAdd(&cursor[rec[i]], 1);
    perm[pos] = i;
    sendP[pos] = send[i];
  }
}

// ---------------- segment-sum of raw edge features (E x 16 fp32) ----------------
__global__ void segsum_raw(const float* __restrict__ eraw, const int* __restrict__ row_ptr,
                           const int* __restrict__ perm, float* __restrict__ out16, int N) {
  int sub = threadIdx.x >> 4;
  int f = threadIdx.x & 15;
  int r = blockIdx.x * 16 + sub;
  if (r >= N) return;
  int j0 = row_ptr[r], j1 = row_ptr[r + 1];
  float s0 = 0.f, s1 = 0.f;
  int j = j0;
  for (; j + 2 <= j1; j += 2) {
    int e0 = perm[j], e1 = perm[j + 1];
    s0 += eraw[(long)e0 * 16 + f];
    s1 += eraw[(long)e1 * 16 + f];
  }
  if (j < j1) s0 += eraw[(long)perm[j] * 16 + f];
  out16[(long)r * 16 + f] = s0 + s1;
}

// ---------------- sender-gather segment sum, 256 cols (4-deep ILP) ----------------
__launch_bounds__(256)
__global__ void gather_sum256(const unsigned short* __restrict__ src,
                              const int* __restrict__ row_ptr, const int* __restrict__ sendP,
                              unsigned short* __restrict__ dst, int N) {
  const int wid = threadIdx.x >> 6, lane = threadIdx.x & 63;
  const int r = blockIdx.x * 4 + wid;
  if (r >= N) return;
  const int j0 = row_ptr[r], j1 = row_ptr[r + 1];
  const int off = lane * 4;
  float a0 = 0.f, a1 = 0.f, a2 = 0.f, a3 = 0.f;
  int j = j0;
  for (; j + 4 <= j1; j += 4) {
    int i0 = sendP[j], i1 = sendP[j + 1], i2 = sendP[j + 2], i3 = sendP[j + 3];
    us4 x = *reinterpret_cast<const us4*>(&src[(long)i0 * 256 + off]);
    us4 y = *reinterpret_cast<const us4*>(&src[(long)i1 * 256 + off]);
    us4 z = *reinterpret_cast<const us4*>(&src[(long)i2 * 256 + off]);
    us4 w = *reinterpret_cast<const us4*>(&src[(long)i3 * 256 + off]);
    a0 += b2f(x[0]) + b2f(y[0]) + b2f(z[0]) + b2f(w[0]);
    a1 += b2f(x[1]) + b2f(y[1]) + b2f(z[1]) + b2f(w[1]);
    a2 += b2f(x[2]) + b2f(y[2]) + b2f(z[2]) + b2f(w[2]);
    a3 += b2f(x[3]) + b2f(y[3]) + b2f(z[3]) + b2f(w[3]);
  }
  for (; j < j1; ++j) {
    us4 x = *reinterpret_cast<const us4*>(&src[(long)sendP[j] * 256 + off]);
    a0 += b2f(x[0]); a1 += b2f(x[1]); a2 += b2f(x[2]); a3 += b2f(x[3]);
  }
  us4 o;
  o[0] = f2b(a0); o[1] = f2b(a1); o[2] = f2b(a2); o[3] = f2b(a3);
  *reinterpret_cast<us4*>(&dst[(long)r * 256 + off]) = o;
}

// ---------------- sender-gather segment sum, 128 cols, 2 edges/wave-pass, 4-deep ILP --------
__launch_bounds__(256)
__global__ void gather_sum128(const unsigned short* __restrict__ src, int col,
                              const int* __restrict__ row_ptr, const int* __restrict__ sendP,
                              unsigned short* __restrict__ dst, int N) {
  const int wid = threadIdx.x >> 6, lane = threadIdx.x & 63;
  const int r = blockIdx.x * 4 + wid;
  if (r >= N) return;
  const int j0 = row_ptr[r], j1 = row_ptr[r + 1];
  const int half = lane >> 5;
  const int c = lane & 31;
  const int off = col + c * 4;
  float a0 = 0.f, a1 = 0.f, a2 = 0.f, a3 = 0.f;
  float b0 = 0.f, b1 = 0.f, b2 = 0.f, b3 = 0.f;
  int j = j0 + half;
  for (; j + 6 < j1; j += 8) {
    int i0 = sendP[j], i1 = sendP[j + 2], i2 = sendP[j + 4], i3 = sendP[j + 6];
    us4 x = *reinterpret_cast<const us4*>(&src[(long)i0 * 256 + off]);
    us4 y = *reinterpret_cast<const us4*>(&src[(long)i1 * 256 + off]);
    us4 z = *reinterpret_cast<const us4*>(&src[(long)i2 * 256 + off]);
    us4 w = *reinterpret_cast<const us4*>(&src[(long)i3 * 256 + off]);
    a0 += b2f(x[0]) + b2f(z[0]); a1 += b2f(x[1]) + b2f(z[1]);
    a2 += b2f(x[2]) + b2f(z[2]); a3 += b2f(x[3]) + b2f(z[3]);
    b0 += b2f(y[0]) + b2f(w[0]); b1 += b2f(y[1]) + b2f(w[1]);
    b2 += b2f(y[2]) + b2f(w[2]); b3 += b2f(y[3]) + b2f(w[3]);
  }
  for (; j + 2 < j1; j += 4) {
    int i0 = sendP[j], i1 = sendP[j + 2];
    us4 x = *reinterpret_cast<const us4*>(&src[(long)i0 * 256 + off]);
    us4 y = *reinterpret_cast<const us4*>(&src[(long)i1 * 256 + off]);
    a0 += b2f(x[0]); a1 += b2f(x[1]); a2 += b2f(x[2]); a3 += b2f(x[3]);
    b0 += b2f(y[0]); b1 += b2f(y[1]); b2 += b2f(y[2]); b3 += b2f(y[3]);
  }
  if (j < j1) {
    us4 x = *reinterpret_cast<const us4*>(&src[(long)sendP[j] * 256 + off]);
    a0 += b2f(x[0]); a1 += b2f(x[1]); a2 += b2f(x[2]); a3 += b2f(x[3]);
  }
  a0 += b0; a1 += b1; a2 += b2; a3 += b3;
  a0 += __shfl_xor(a0, 32); a1 += __shfl_xor(a1, 32);
  a2 += __shfl_xor(a2, 32); a3 += __shfl_xor(a3, 32);
  if (half == 0) {
    us4 o;
    o[0] = f2b(a0); o[1] = f2b(a1); o[2] = f2b(a2); o[3] = f2b(a3);
    *reinterpret_cast<us4*>(&dst[(long)r * 256 + off]) = o;
  }
}

// ---------------- node-level multi-section MFMA GEMM, 32-col staging (R14 structure) -------
__launch_bounds__(256, 3)
__global__ void gemm_mp(int M, int nsrc, int Kw, int srcsel, int coloffs, int sflags,
                        const unsigned short* __restrict__ sp0, const unsigned short* __restrict__ sp1,
                        const unsigned short* __restrict__ sp2,
                        const unsigned short* __restrict__ Wb,
                        const float* __restrict__ bdeg, const float* __restrict__ bone,
                        const float* __restrict__ degF,
                        unsigned short* __restrict__ outB, int ostride, int ocoloff,
                        float* __restrict__ outF) {
  __shared__ __align__(16) unsigned short ldsW[8 * 64 * 8];  // 8KB fragment-order chunk
  const int tid = threadIdx.x;
  const int wid = tid >> 6, lane = tid & 63;
  const long rowBase = (long)blockIdx.x * 128 + wid * 32;
  const int lq = lane >> 4;
  const int lr = lane & 15;

  int rowD[2];
  float degD[2];
#pragma unroll
  for (int am = 0; am < 2; ++am) {
    long e = rowBase + am * 16 + lr;
    if (e >= M) e = M - 1;
    rowD[am] = (int)e;
    degD[am] = degF[rowD[am]];
  }

  f32x4 acc[2][8];
#pragma unroll
  for (int i = 0; i < 2; ++i)
#pragma unroll
    for (int j = 0; j < 8; ++j) acc[i][j] = 0.f;

  int wcol = 0;
  for (int si = 0; si < nsrc; ++si) {
    const int sel = (srcsel >> (si * 4)) & 15;
    const unsigned short* sp = (sel == 0) ? sp0 : (sel == 1) ? sp1 : sp2;
    const long astride = (sel == 2) ? 128 : 256;
    const int acoloff = ((coloffs >> (si * 4)) & 15) * 128;
    const int f = (sflags >> (si * 4)) & 15;
    const int nrep = (f == 1) ? 2 : 1;
#pragma unroll 4
    for (int sub = 0; sub < 4; ++sub) {
      const int koff = acoloff + sub * 32 + lq * 8;
      bf16x8 a[2];
#pragma unroll
      for (int am = 0; am < 2; ++am)
        a[am] = *reinterpret_cast<const bf16x8*>(&sp[(long)rowD[am] * astride + koff]);
      for (int rep = 0; rep < nrep; ++rep) {
        const bool sc = (f == 2) || (rep == 1);
        const int wk = wcol + rep * 128 + sub * 32;
        __syncthreads();  // WAR: previous chunk's LDS reads done
#pragma unroll
        for (int it = 0; it < 2; ++it) {
          int idx = tid + it * 256;
          int t = idx >> 6, l = idx & 63;
          int n = t * 16 + (l & 15);
          int kk = wk + ((l >> 4) * 8);
          *reinterpret_cast<bf16x8*>(&ldsW[idx * 8]) =
              *reinterpret_cast<const bf16x8*>(&Wb[(long)n * Kw + kk]);
        }
        __syncthreads();
        bf16x8 av0 = sc ? scale8(a[0], degD[0]) : a[0];
        bf16x8 av1 = sc ? scale8(a[1], degD[1]) : a[1];
#pragma unroll
        for (int n = 0; n < 8; ++n) {
          bf16x8 b = *reinterpret_cast<const bf16x8*>(&ldsW[(n * 64 + lane) * 8]);
          acc[0][n] = __builtin_amdgcn_mfma_f32_16x16x32_bf16(av0, b, acc[0][n], 0, 0, 0);
          acc[1][n] = __builtin_amdgcn_mfma_f32_16x16x32_bf16(av1, b, acc[1][n], 0, 0, 0);
        }
      }
    }
    wcol += nrep * 128;
  }

  float bd[8], bo[8];
#pragma unroll
  for (int n = 0; n < 8; ++n) {
    bd[n] = bdeg ? bdeg[n * 16 + lr] : 0.f;
    bo[n] = bone ? bone[n * 16 + lr] : 0.f;
  }

  // C layout (16x16x32 bf16): col = lane&15, row = (lane>>4)*4 + reg
#pragma unroll
  for (int am = 0; am < 2; ++am) {
#pragma unroll
    for (int r = 0; r < 4; ++r) {
      long row = rowBase + am * 16 + lq * 4 + r;
      if (row < M) {
        float d = degF[row];
        long ob = row * ostride + ocoloff;
#pragma unroll
        for (int n = 0; n < 8; ++n) {
          float v = acc[am][n][r] + bd[n] * d + bo[n];
          outB[ob + n * 16 + lr] = f2b(v);
          if (outF) outF[row * 128 + n * 16 + lr] = v;
        }
      }
    }
  }
}

// ---------------- per-graph aggregation v2: wave-per-32-row slab, us4 loads ----------------
__launch_bounds__(256)
__global__ void readout_agg(const unsigned short* __restrict__ hp,
                            const int* __restrict__ batch, float* __restrict__ hep, int N) {
  const int wid = threadIdx.x >> 6, lane = threadIdx.x & 63;
  const int n0 = blockIdx.x * 128 + wid * 32;
  if (n0 >= N) return;
  int n1 = n0 + 32; if (n1 > N) n1 = N;
  const int off = lane * 4;
  float s0 = 0.f, s1 = 0.f, s2 = 0.f, s3 = 0.f;
  int curg = -1;
  for (int n = n0; n < n1; ++n) {
    int g = batch[n];
    if (g != curg) {
      if (curg >= 0) {
        float* dst = &hep[(long)curg * 256 + off];
        unsafeAtomicAdd(dst + 0, s0); unsafeAtomicAdd(dst + 1, s1);
        unsafeAtomicAdd(dst + 2, s2); unsafeAtomicAdd(dst + 3, s3);
      }
      curg = g; s0 = s1 = s2 = s3 = 0.f;
    }
    us4 v = *reinterpret_cast<const us4*>(&hp[(long)n * 256 + off]);
    s0 += b2f(v[0]); s1 += b2f(v[1]); s2 += b2f(v[2]); s3 += b2f(v[3]);
  }
  if (curg >= 0) {
    float* dst = &hep[(long)curg * 256 + off];
    unsafeAtomicAdd(dst + 0, s0); unsafeAtomicAdd(dst + 1, s1);
    unsafeAtomicAdd(dst + 2, s2); unsafeAtomicAdd(dst + 3, s3);
  }
}

// ---------------- readout MLP: one block per graph ----------------
__global__ void mlp_kernel(const float* __restrict__ hep,
                           const float* __restrict__ r1w, const float* __restrict__ r1b,
                           const float* __restrict__ r2w, const float* __restrict__ r2b,
                           const float* __restrict__ r3w, const float* __restrict__ r3b,
                           float* __restrict__ out) {
  int g = blockIdx.x, t = threadIdx.x;  // 128 threads
  __shared__ float x[256];
  __shared__ float y[128];
  __shared__ float z[64];
  x[t] = hep[(long)g * 256 + t];
  x[t + 128] = hep[(long)g * 256 + 128 + t];
  __syncthreads();
  float s = r1b[t];
  for (int k = 0; k < 256; ++k) s += r1w[t * 256 + k] * x[k];
  y[t] = fmaxf(s, 0.f);
  __syncthreads();
  if (t < 64) {
    float s2 = r2b[t];
    for (int k = 0; k < 128; ++k) s2 += r2w[t * 128 + k] * y[k];
    z[t] = fmaxf(s2, 0.f);
  }
  __syncthreads();
  if (t == 0) {
    float s3 = r3b[0];
    for (int k = 0; k < 64; ++k) s3 += r3w[k] * z[k];
    out[g] = s3;
  }
}

extern "C" void kernel_launch(void* const* d_in, const int* in_sizes, int n_in,
                              void* d_out, int out_size, void* d_ws, size_t ws_size,
                              hipStream_t stream) {
  const float* h_in = (const float*)d_in[0];
  const float* e_in = (const float*)d_in[1];
  const float* p_in = (const float*)d_in[2];
  const int* ei = (const int*)d_in[3];
  const int* batch = (const int*)d_in[4];
  const float* he_w = (const float*)d_in[5];  const float* he_b = (const float*)d_in[6];
  const float* ee_w = (const float*)d_in[7];  const float* ee_b = (const float*)d_in[8];
  const float* pe_w = (const float*)d_in[9];  const float* pe_b = (const float*)d_in[10];
  const float* hu_w = (const float*)d_in[11]; const float* hu_b = (const float*)d_in[12];
  const float* eu_w = (const float*)d_in[13]; const float* eu_b = (const float*)d_in[14];
  const float* pu_w = (const float*)d_in[15]; const float* pu_b = (const float*)d_in[16];
  const float* hg_w = (const float*)d_in[17]; const float* hg_b = (const float*)d_in[18];
  const float* pg_w = (const float*)d_in[19]; const float* pg_b = (const float*)d_in[20];
  const float* r1w = (const float*)d_in[21];  const float* r1b = (const float*)d_in[22];
  const float* r2w = (const float*)d_in[23];  const float* r2b = (const float*)d_in[24];
  const float* r3w = (const float*)d_in[25];  const float* r3b = (const float*)d_in[26];

  const int N = 50000, E = 400000, G = 256;
  const int* send = ei;
  const int* rec = ei + E;

  char* ws = (char*)d_ws;
  size_t off = 0;
  auto alloc = [&](size_t bytes) {
    void* pp = ws + off;
    off += (bytes + 255) & ~(size_t)255;
    return pp;
  };
  unsigned short* hp  = (unsigned short*)alloc((size_t)N * 256 * 2);  // [h|p]
  unsigned short* gHP = (unsigned short*)alloc((size_t)N * 256 * 2);  // [sum h[send] | sum p[send]]
  unsigned short* sT  = (unsigned short*)alloc((size_t)N * 128 * 2);  // s = sum_in e
  unsigned short* hb16 = (unsigned short*)alloc((size_t)N * 64 * 2);  // h_in as bf16
  unsigned short* pb32 = (unsigned short*)alloc((size_t)N * 32 * 2);  // p_in as bf16 [N,32] padded
  unsigned short* sb32 = (unsigned short*)alloc((size_t)N * 32 * 2);  // segsum as bf16 [N,32] padded
  unsigned short* w_he = (unsigned short*)alloc((size_t)128 * 64 * 2);
  unsigned short* w_pe = (unsigned short*)alloc((size_t)128 * 32 * 2); // padded
  unsigned short* w_ee = (unsigned short*)alloc((size_t)128 * 32 * 2); // padded
  float* segsumF = (float*)alloc((size_t)N * 16 * 4);
  int* deg = (int*)alloc((size_t)N * 4);
  int* row_ptr = (int*)alloc((size_t)(N + 1) * 4);
  int* cursor = (int*)alloc((size_t)N * 4);
  int* blkSum = (int*)alloc((size_t)64 * 4);
  int* perm = (int*)alloc((size_t)E * 4);
  int* sendP = (int*)alloc((size_t)E * 4);
  float* degF = (float*)alloc((size_t)N * 4);
  float* hep = (float*)alloc((size_t)G * 256 * 4);
  unsigned short* w_h2 = (unsigned short*)alloc((size_t)4 * 128 * 768 * 2);
  unsigned short* w_p2 = (unsigned short*)alloc((size_t)4 * 128 * 512 * 2);
  unsigned short* w_eu = (unsigned short*)alloc((size_t)4 * 128 * 384 * 2);
  float* bh1 = (float*)alloc((size_t)4 * 128 * 4);
  float* bp1 = (float*)alloc((size_t)4 * 128 * 4);
  (void)ws_size; (void)n_in; (void)in_sizes; (void)out_size;

  // conversions + composed weights
  f2b_kernel<<<192, 256, 0, stream>>>(eu_w, w_eu, 4 * 128 * 384 / 4);
  f2b_kernel<<<2048, 256, 0, stream>>>(h_in, hb16, N * 64 / 4);
  f2b_kernel<<<8, 256, 0, stream>>>(he_w, w_he, 128 * 64 / 4);
  f2b_pad32<<<128, 256, 0, stream>>>(pe_w, w_pe, 128);
  f2b_pad32<<<128, 256, 0, stream>>>(ee_w, w_ee, 128);
  f2b_pad32<<<2048, 256, 0, stream>>>(p_in, pb32, N);
  compose_w<<<128, 256, 0, stream>>>(hg_w, hu_w, pg_w, pu_w, hu_b, pu_b, w_h2, w_p2, bh1, bp1);

  // CSR by rec (+ pre-permuted sender index); hierarchical scan
  const int nb = (N + 1023) / 1024;  // 49
  hipMemsetAsync(deg, 0, (size_t)N * 4, stream);
  count_deg<<<(E + 255) / 256, 256, 0, stream>>>(rec, deg, E);
  scan_blk<<<nb, 256, 0, stream>>>(deg, row_ptr, blkSum, N);
  scan_top<<<1, 64, 0, stream>>>(blkSum, nb);
  scan_fix<<<nb, 256, 0, stream>>>(deg, row_ptr, blkSum, cursor, degF, N, E);
  scatter_perm<<<(E + 255) / 256, 256, 0, stream>>>(rec, send, cursor, perm, sendP, E);

  // embeddings (all MFMA now)
  embed_mfma64<<<(N + 127) / 128, 256, 0, stream>>>(hb16, w_he, he_b, hp, N);
  embed_mfma32<<<(N + 127) / 128, 256, 0, stream>>>(pb32, w_pe, pe_b, hp, N, 256, 128, nullptr);
  // s_0 = ee_w @ (sum_in e_raw) + deg*ee_b   (e stays virtual forever)
  segsum_raw<<<(N + 15) / 16, 256, 0, stream>>>(e_in, row_ptr, perm, segsumF, N);
  f2b_pad32<<<2048, 256, 0, stream>>>(segsumF, sb32, N);
  embed_mfma32<<<(N + 127) / 128, 256, 0, stream>>>(sb32, w_ee, ee_b, sT, N, 128, 0, degF);

  // initial sender-gather of [h|p]
  gather_sum256<<<(N + 3) / 4, 256, 0, stream>>>(hp, row_ptr, sendP, gHP, N);

  float* pOut = (float*)d_out + 256;
  const int gridN = (N + 127) / 128;  // 391
  const int gridG = (N + 3) / 4;      // 12500

  for (int l = 0; l < 4; ++l) {
    // h' = W_h2 @ [gH, gP, s, h(+deg·h), deg·p] + deg*bh1 + hg_b  (in-place)
    gemm_mp<<<gridN, 256, 0, stream>>>(N, 5, 768, 0x11200, 0x10010, 0x21000,
        gHP, hp, sT,
        w_h2 + (size_t)l * 128 * 768, bh1 + l * 128, hg_b + l * 128, degF,
        hp, 256, 0, nullptr);
    // gH' = Σ h'[send]
    gather_sum128<<<gridG, 256, 0, stream>>>(hp, 0, row_ptr, sendP, gHP, N);
    // s' = EU @ [gH', deg·h', s] + deg*eu_b
    gemm_mp<<<gridN, 256, 0, stream>>>(N, 3, 384, 0x210, 0x000, 0x020,
        gHP, hp, sT,
        w_eu + (size_t)l * 128 * 384, eu_b + l * 128, nullptr, degF,
        sT, 128, 0, nullptr);
    // p' = W_p2 @ [gP, s', p(+deg·p)] + deg*bp1 + pg_b  (in-place; last layer -> fp32 out)
    gemm_mp<<<gridN, 256, 0, stream>>>(N, 3, 512, 0x120, 0x101, 0x100,
        gHP, hp, sT,
        w_p2 + (size_t)l * 128 * 512, bp1 + l * 128, pg_b + l * 128, degF,
        hp, 256, 128, (l == 3) ? pOut : nullptr);
    // gP' = Σ p'[send]  (not needed after last layer)
    if (l < 3)
      gather_sum128<<<gridG, 256, 0, stream>>>(hp, 128, row_ptr, sendP, gHP, N);
  }

  hipMemsetAsync(hep, 0, (size_t)G * 256 * 4, stream);
  readout_agg<<<(N + 127) / 128, 256, 0, stream>>>(hp, batch, hep, N);
  mlp_kernel<<<G, 128, 0, stream>>>(hep, r1w, r1b, r2w, r2b, r3w, r3b, (float*)d_out);
}